// Round 6
// baseline (713.612 us; speedup 1.0000x reference)
//
#include <hip/hip_runtime.h>
#include <hip/hip_bf16.h>

// Hierarchical 1-2-GNN forward. B=64 graphs x 64 nodes, P=129024 pairs, HID=128.
// Round 6: dispatch-count attack.
//  - One persistent cooperative kernel (256 blocks, software grid barrier with
//    device-scope fences) runs: zero+convert+weight-swizzle, CSR count/scan/fill,
//    3 node MP layers (MFMA GEMM + gather), seg_sum(N) fused into last gather,
//    and the 4 HU/HV GEMMs.  (17 launches -> 1)
//  - seg_sum(P) fused into the final pair gather (H2 final write+read removed).
//  - Total launches: 6 (memset(4B), persist, gather_two0, gemmP, gather+seg, cls).

typedef short s16x8 __attribute__((ext_vector_type(8)));
typedef float f32x4 __attribute__((ext_vector_type(4)));

__device__ __forceinline__ unsigned short f2bf(float f) {
  union { float f; unsigned u; } x; x.f = f;
  unsigned r = (x.u + 0x7fffu + ((x.u >> 16) & 1u)) >> 16;   // RNE
  return (unsigned short)r;
}
__device__ __forceinline__ float bf2f(unsigned short h) {
  union { unsigned u; float f; } x; x.u = ((unsigned)h) << 16;
  return x.f;
}
__device__ __forceinline__ float4 ldbf4(const unsigned short* p) {
  ushort4 q = *(const ushort4*)p;
  return make_float4(bf2f(q.x), bf2f(q.y), bf2f(q.z), bf2f(q.w));
}
__device__ __forceinline__ void stbf4(unsigned short* p, float4 v) {
  ushort4 q;
  q.x = f2bf(v.x); q.y = f2bf(v.y); q.z = f2bf(v.z); q.w = f2bf(v.w);
  *(ushort4*)p = q;
}
__device__ __forceinline__ float4 ld4(const float* p) { return *(const float4*)p; }

// ---------------- grid barrier (monotone counter; device-scope fences) ----------------
__device__ __forceinline__ void gbar(int* cnt, int nb, int& tgt) {
  __syncthreads();
  if (threadIdx.x == 0) {
    tgt += nb;
    __threadfence();                                   // release: my block's writes
    __hip_atomic_fetch_add(cnt, 1, __ATOMIC_ACQ_REL, __HIP_MEMORY_SCOPE_AGENT);
    while (__hip_atomic_load(cnt, __ATOMIC_RELAXED, __HIP_MEMORY_SCOPE_AGENT) < tgt)
      __builtin_amdgcn_s_sleep(1);
  }
  __syncthreads();
  __threadfence();                                     // acquire: drop stale lines
}

// ---------------- dual MFMA GEMM tile (device fn) ----------------
// C[tile*64 .. +64, 0..128] = A @ W for two W simultaneously.
template<int KCS>
__device__ __forceinline__ void gemm_tile(
    const unsigned short* __restrict__ A, const unsigned short* __restrict__ Wfrag,
    unsigned short* __restrict__ Ca, unsigned short* __restrict__ Cb,
    int tile, unsigned short (*sOut)[136])
{
  const int K = KCS * 32;
  const int tid = threadIdx.x;
  const int lane = tid & 63;
  const int wv = tid >> 6;
  const long rowBase = (long)tile * 64;

  f32x4 accA[8], accB[8];
#pragma unroll
  for (int i = 0; i < 8; ++i) { accA[i] = (f32x4)0.0f; accB[i] = (f32x4)0.0f; }

  const unsigned short* aptr =
      A + (size_t)(rowBase + wv * 16 + (lane & 15)) * K + ((lane >> 4) << 3);
  const unsigned short* wptr = Wfrag + (size_t)lane * 8;

#pragma unroll
  for (int kc = 0; kc < KCS; ++kc) {
    s16x8 af = *(const s16x8*)(aptr + kc * 32);
#pragma unroll
    for (int nt = 0; nt < 8; ++nt) {
      s16x8 b0 = *(const s16x8*)(wptr + ((size_t)((0 * 8 + nt) * KCS + kc) << 9));
      s16x8 b1 = *(const s16x8*)(wptr + ((size_t)((1 * 8 + nt) * KCS + kc) << 9));
      accA[nt] = __builtin_amdgcn_mfma_f32_16x16x32_bf16(af, b0, accA[nt], 0, 0, 0);
      accB[nt] = __builtin_amdgcn_mfma_f32_16x16x32_bf16(af, b1, accB[nt], 0, 0, 0);
    }
  }

  const int colb = lane & 15;
  const int row0 = wv * 16 + ((lane >> 4) << 2);
#pragma unroll
  for (int sel = 0; sel < 2; ++sel) {
    __syncthreads();
#pragma unroll
    for (int nt = 0; nt < 8; ++nt) {
      f32x4 v = sel ? accB[nt] : accA[nt];
#pragma unroll
      for (int r = 0; r < 4; ++r)
        sOut[row0 + r][nt * 16 + colb] = f2bf(v[r]);
    }
    __syncthreads();
    unsigned short* C = sel ? Cb : Ca;
#pragma unroll
    for (int i = 0; i < 4; ++i) {
      int fi = tid + i * 256;
      int row = fi >> 4;
      int c8 = fi & 15;
      *(uint4*)(C + (rowBase + row) * 128 + c8 * 8) = *(uint4*)&sOut[row][c8 * 8];
    }
  }
}

// ---------------- persistent all-in-one node-stage kernel ----------------
struct PArgs {
  const float* x;
  const float* wa[6];
  const float* wb[6];
  const int* ei; const int* te; const int* pu; const int* pv;
  const float* iso;
  unsigned short *xb, *hb, *preN, *msgN, *HU1, *HV1, *HU2, *HV2;
  unsigned short* Wf[6];
  int *degN, *degP, *offN, *curN, *eidxN, *offP, *curP;
  int4* recP;
  int *bsumP, *bsumN;
  float *ge1, *ge2;
  int* cnt;
  int N, E1, P, E2;
};

__device__ __forceinline__ float4 gather_row(
    const unsigned short* __restrict__ pre, const unsigned short* __restrict__ msg,
    const int* __restrict__ off, const int* __restrict__ eidx, int r, int f)
{
  float4 acc = ldbf4(pre + (size_t)r * 128 + f);
  int j = off[r], e1 = off[r + 1];
  for (; j + 1 < e1; j += 2) {
    int s0 = eidx[j], s1 = eidx[j + 1];
    float4 m0 = ldbf4(msg + (size_t)s0 * 128 + f);
    float4 m1 = ldbf4(msg + (size_t)s1 * 128 + f);
    acc.x += m0.x + m1.x; acc.y += m0.y + m1.y;
    acc.z += m0.z + m1.z; acc.w += m0.w + m1.w;
  }
  if (j < e1) {
    int s0 = eidx[j];
    float4 m0 = ldbf4(msg + (size_t)s0 * 128 + f);
    acc.x += m0.x; acc.y += m0.y; acc.z += m0.z; acc.w += m0.w;
  }
  return make_float4(fmaxf(acc.x, 0.f), fmaxf(acc.y, 0.f),
                     fmaxf(acc.z, 0.f), fmaxf(acc.w, 0.f));
}

__global__ __launch_bounds__(256) void persist_all(PArgs a)
{
  __shared__ __align__(16) unsigned short smem[64 * 136];   // 17408 B, phase-shared
  unsigned short (*sOut)[136] = (unsigned short(*)[136])smem;
  int* sInt = (int*)smem;
  float* sF = (float*)smem;

  const int b = blockIdx.x;          // 256 blocks
  const int t = threadIdx.x;         // 256 threads
  const int gtid = b * 256 + t;
  const int GT = 65536;
  int tgt = 0;

  // ---- phase 0: zero deg + ge, convert x->bf16, swizzle weights ----
  for (int i = gtid; i < a.N + a.P; i += GT) a.degN[i] = 0;     // degN,degP contiguous
  for (int i = gtid; i < 2 * 8192; i += GT) a.ge1[i] = 0.f;     // ge1,ge2 contiguous
  for (int i = gtid; i < a.N * 16; i += GT)
    stbf4(a.xb + (size_t)i * 4, ld4(a.x + (size_t)i * 4));
  if (gtid < 22528) {                                           // 2048 + 5*4096 frags
    int p, local, kcs, kclog;
    if (gtid < 2048) { p = 0; local = gtid; kcs = 2; kclog = 1; }
    else { int r = gtid - 2048; p = 1 + (r >> 12); local = r & 4095; kcs = 4; kclog = 2; }
    int lane = local & 63;
    int t1 = local >> 6;
    int kc = t1 & (kcs - 1);
    int t2 = t1 >> kclog;
    int nt = t2 & 7;
    int wsel = t2 >> 3;
    const float* W = wsel ? a.wb[p] : a.wa[p];
    int k0 = kc * 32 + ((lane >> 4) << 3);
    int n = nt * 16 + (lane & 15);
    unsigned short tmp[8];
#pragma unroll
    for (int j = 0; j < 8; ++j) tmp[j] = f2bf(W[(size_t)(k0 + j) * 128 + n]);
    *(uint4*)(a.Wf[p] + (size_t)local * 8) = *(uint4*)tmp;
  }
  gbar(a.cnt, 256, tgt);

  // ---- phase 1: degree count ----
  for (int e = gtid; e < a.E1 + a.E2; e += GT) {
    if (e < a.E1) atomicAdd(&a.degN[a.ei[a.E1 + e]], 1);
    else { int i = e - a.E1; atomicAdd(&a.degP[a.te[a.E2 + i]], 1); }
  }
  gbar(a.cnt, 256, tgt);

  // ---- phase 2a: per-block local scans (P chunk 504, N chunk 16) ----
  {
    int base = b * 504;
    int v0 = 0, v1 = 0;
    if (t < 252) { v0 = a.degP[base + t * 2]; v1 = a.degP[base + t * 2 + 1]; }
    sInt[t] = v0 + v1;
    __syncthreads();
    for (int d = 1; d < 256; d <<= 1) {
      int v = (t >= d) ? sInt[t - d] : 0;
      __syncthreads();
      sInt[t] += v;
      __syncthreads();
    }
    int ex = t ? sInt[t - 1] : 0;
    if (t < 252) { a.offP[base + t * 2] = ex; a.offP[base + t * 2 + 1] = ex + v0; }
    if (t == 255) a.bsumP[b] = sInt[255];
    if (t == 0) {
      int nb = b * 16, run = 0;
      for (int i = 0; i < 16; ++i) { int v = a.degN[nb + i]; a.offN[nb + i] = run; run += v; }
      a.bsumN[b] = run;
    }
  }
  gbar(a.cnt, 256, tgt);

  // ---- phase 2c: block 0 scans the 256 block totals (P then N) ----
  if (b == 0) {
    sInt[t] = a.bsumP[t];
    __syncthreads();
    for (int d = 1; d < 256; d <<= 1) {
      int v = (t >= d) ? sInt[t - d] : 0;
      __syncthreads();
      sInt[t] += v;
      __syncthreads();
    }
    int exP = t ? sInt[t - 1] : 0;
    int totP = sInt[255];
    __syncthreads();
    a.bsumP[t] = exP;
    if (t == 255) a.offP[a.P] = totP;
    sInt[t] = a.bsumN[t];
    __syncthreads();
    for (int d = 1; d < 256; d <<= 1) {
      int v = (t >= d) ? sInt[t - d] : 0;
      __syncthreads();
      sInt[t] += v;
      __syncthreads();
    }
    int exN = t ? sInt[t - 1] : 0;
    if (t == 255) a.offN[a.N] = sInt[255];
    a.bsumN[t] = exN;
  }
  gbar(a.cnt, 256, tgt);

  // ---- phase 2d: add block bases, write cursor copies ----
  {
    int baseP = a.bsumP[b];
    int base = b * 504;
    for (int i = t; i < 504; i += 256) {
      int v = a.offP[base + i] + baseP;
      a.offP[base + i] = v; a.curP[base + i] = v;
    }
    int baseN = a.bsumN[b];
    int nb = b * 16;
    if (t < 16) {
      int v = a.offN[nb + t] + baseN;
      a.offN[nb + t] = v; a.curN[nb + t] = v;
    }
  }
  gbar(a.cnt, 256, tgt);

  // ---- phase 3: CSR fill (node: src idx; pair: packed record) ----
  for (int e = gtid; e < a.E1 + a.E2; e += GT) {
    if (e < a.E1) {
      int s = a.ei[e], d = a.ei[a.E1 + e];
      int pos = atomicAdd(&a.curN[d], 1);
      a.eidxN[pos] = s;
    } else {
      int i = e - a.E1;
      int s = a.te[i], d = a.te[a.E2 + i];
      int pos = atomicAdd(&a.curP[d], 1);
      a.recP[pos] = make_int4(a.pu[s], a.pv[s], __float_as_int(a.iso[s]), s);
    }
  }
  gbar(a.cnt, 256, tgt);

  // ---- node MP layer 0 ----
  if (b < 64) gemm_tile<2>(a.xb, a.Wf[0], a.preN, a.msgN, b, sOut);
  gbar(a.cnt, 256, tgt);
  {
    int grp = t >> 5, f = (t & 31) * 4;
#pragma unroll
    for (int rr = 0; rr < 2; ++rr) {
      int r = b * 16 + grp * 2 + rr;
      float4 o = gather_row(a.preN, a.msgN, a.offN, a.eidxN, r, f);
      stbf4(a.hb + (size_t)r * 128 + f, o);
    }
  }
  gbar(a.cnt, 256, tgt);

  // ---- node MP layer 1 ----
  if (b < 64) gemm_tile<4>(a.hb, a.Wf[1], a.preN, a.msgN, b, sOut);
  gbar(a.cnt, 256, tgt);
  {
    int grp = t >> 5, f = (t & 31) * 4;
#pragma unroll
    for (int rr = 0; rr < 2; ++rr) {
      int r = b * 16 + grp * 2 + rr;
      float4 o = gather_row(a.preN, a.msgN, a.offN, a.eidxN, r, f);
      stbf4(a.hb + (size_t)r * 128 + f, o);
    }
  }
  gbar(a.cnt, 256, tgt);

  // ---- node MP layer 2 (+ fused seg_sum into ge1) ----
  if (b < 64) gemm_tile<4>(a.hb, a.Wf[2], a.preN, a.msgN, b, sOut);
  gbar(a.cnt, 256, tgt);
  {
    if (t < 128) sF[t] = 0.f;
    __syncthreads();
    int grp = t >> 5, f = (t & 31) * 4;
    float4 gacc = make_float4(0.f, 0.f, 0.f, 0.f);
#pragma unroll
    for (int rr = 0; rr < 2; ++rr) {
      int r = b * 16 + grp * 2 + rr;
      float4 o = gather_row(a.preN, a.msgN, a.offN, a.eidxN, r, f);
      stbf4(a.hb + (size_t)r * 128 + f, o);
      gacc.x += o.x; gacc.y += o.y; gacc.z += o.z; gacc.w += o.w;
    }
    atomicAdd(&sF[f + 0], gacc.x);
    atomicAdd(&sF[f + 1], gacc.y);
    atomicAdd(&sF[f + 2], gacc.z);
    atomicAdd(&sF[f + 3], gacc.w);
    __syncthreads();
    if (t < 128) atomicAdd(&a.ge1[(b >> 2) * 128 + t], sF[t]);   // graph = (b*16)/64
  }
  gbar(a.cnt, 256, tgt);

  // ---- HU/HV GEMMs (4 products via 2 dual GEMMs, 128 tile-tasks) ----
  if (b < 64)       gemm_tile<4>(a.hb, a.Wf[3], a.HU1, a.HU2, b, sOut);
  else if (b < 128) gemm_tile<4>(a.hb, a.Wf[4], a.HV1, a.HV2, b - 64, sOut);
}

// ---------------- standalone P-stage kernels ----------------
__global__ __launch_bounds__(256) void gemm_dual_mfma4(
    const unsigned short* __restrict__ A, const unsigned short* __restrict__ Wfrag,
    unsigned short* __restrict__ Ca, unsigned short* __restrict__ Cb)
{
  __shared__ __align__(16) unsigned short sOut[64][136];
  gemm_tile<4>(A, Wfrag, Ca, Cb, blockIdx.x, sOut);
}

// 2-set layer 0, fully fused, packed edge records, unroll x2
__global__ __launch_bounds__(256) void gather_two0_bf(
    const unsigned short* __restrict__ HU1, const unsigned short* __restrict__ HV1,
    const unsigned short* __restrict__ HU2, const unsigned short* __restrict__ HV2,
    const float* __restrict__ iso,
    const float* __restrict__ w1iso, const float* __restrict__ w2iso,
    const int* __restrict__ pu, const int* __restrict__ pv,
    const int* __restrict__ off, const int4* __restrict__ rec,
    unsigned short* __restrict__ out, int P)
{
  int p = blockIdx.x * 8 + (threadIdx.x >> 5);
  if (p >= P) return;
  int f = (threadIdx.x & 31) * 4;
  float4 wi1 = ld4(w1iso + f);
  float4 wi2 = ld4(w2iso + f);
  int u0 = pu[p], v0 = pv[p];
  float is0 = iso[p];
  float4 a = ldbf4(HU1 + (size_t)u0 * 128 + f);
  float4 b = ldbf4(HV1 + (size_t)v0 * 128 + f);
  float4 acc;
  acc.x = a.x + b.x + is0 * wi1.x;
  acc.y = a.y + b.y + is0 * wi1.y;
  acc.z = a.z + b.z + is0 * wi1.z;
  acc.w = a.w + b.w + is0 * wi1.w;
  int j = off[p], e1 = off[p + 1];
  for (; j + 1 < e1; j += 2) {
    int4 r0 = rec[j], r1 = rec[j + 1];
    float4 mu0 = ldbf4(HU2 + (size_t)r0.x * 128 + f);
    float4 mv0 = ldbf4(HV2 + (size_t)r0.y * 128 + f);
    float4 mu1 = ldbf4(HU2 + (size_t)r1.x * 128 + f);
    float4 mv1 = ldbf4(HV2 + (size_t)r1.y * 128 + f);
    float i0 = __int_as_float(r0.z), i1 = __int_as_float(r1.z);
    acc.x += mu0.x + mv0.x + i0 * wi2.x + mu1.x + mv1.x + i1 * wi2.x;
    acc.y += mu0.y + mv0.y + i0 * wi2.y + mu1.y + mv1.y + i1 * wi2.y;
    acc.z += mu0.z + mv0.z + i0 * wi2.z + mu1.z + mv1.z + i1 * wi2.z;
    acc.w += mu0.w + mv0.w + i0 * wi2.w + mu1.w + mv1.w + i1 * wi2.w;
  }
  if (j < e1) {
    int4 r0 = rec[j];
    float4 mu0 = ldbf4(HU2 + (size_t)r0.x * 128 + f);
    float4 mv0 = ldbf4(HV2 + (size_t)r0.y * 128 + f);
    float i0 = __int_as_float(r0.z);
    acc.x += mu0.x + mv0.x + i0 * wi2.x;
    acc.y += mu0.y + mv0.y + i0 * wi2.y;
    acc.z += mu0.z + mv0.z + i0 * wi2.z;
    acc.w += mu0.w + mv0.w + i0 * wi2.w;
  }
  stbf4(out + (size_t)p * 128 + f,
        make_float4(fmaxf(acc.x, 0.f), fmaxf(acc.y, 0.f),
                    fmaxf(acc.z, 0.f), fmaxf(acc.w, 0.f)));
}

// final pair layer gather + relu fused with segment sum into ge2 (no H2 write).
// grid = B*16 blocks; block handles 126 rows of one graph.
__global__ __launch_bounds__(256) void gather_rec_segsum(
    const unsigned short* __restrict__ pre, const unsigned short* __restrict__ msg,
    const int* __restrict__ off, const int4* __restrict__ rec,
    float* __restrict__ ge2, int ppg)
{
  __shared__ float sF[128];
  int t = threadIdx.x;
  if (t < 128) sF[t] = 0.f;
  __syncthreads();
  int g = blockIdx.x >> 4;
  int sub = blockIdx.x & 15;
  int r0 = g * ppg + sub * 126;
  int grp = t >> 5;
  int f = (t & 31) * 4;
  float4 gacc = make_float4(0.f, 0.f, 0.f, 0.f);
  for (int rr = grp; rr < 126; rr += 8) {
    int r = r0 + rr;
    float4 acc = ldbf4(pre + (size_t)r * 128 + f);
    int j = off[r], e1 = off[r + 1];
    for (; j + 1 < e1; j += 2) {
      int4 q0 = rec[j], q1 = rec[j + 1];
      float4 m0 = ldbf4(msg + (size_t)q0.w * 128 + f);
      float4 m1 = ldbf4(msg + (size_t)q1.w * 128 + f);
      acc.x += m0.x + m1.x; acc.y += m0.y + m1.y;
      acc.z += m0.z + m1.z; acc.w += m0.w + m1.w;
    }
    if (j < e1) {
      int4 q0 = rec[j];
      float4 m0 = ldbf4(msg + (size_t)q0.w * 128 + f);
      acc.x += m0.x; acc.y += m0.y; acc.z += m0.z; acc.w += m0.w;
    }
    gacc.x += fmaxf(acc.x, 0.f); gacc.y += fmaxf(acc.y, 0.f);
    gacc.z += fmaxf(acc.z, 0.f); gacc.w += fmaxf(acc.w, 0.f);
  }
  atomicAdd(&sF[f + 0], gacc.x);
  atomicAdd(&sF[f + 1], gacc.y);
  atomicAdd(&sF[f + 2], gacc.z);
  atomicAdd(&sF[f + 3], gacc.w);
  __syncthreads();
  if (t < 128) atomicAdd(&ge2[g * 128 + t], sF[t]);
}

__global__ void classifier(const float* __restrict__ ge1, const float* __restrict__ ge2,
                           const float* __restrict__ W0, const float* __restrict__ b0,
                           const float* __restrict__ W1, const float* __restrict__ b1,
                           float* __restrict__ out)
{
  __shared__ float comb[256];
  __shared__ float hc[128];
  int g = blockIdx.x, t = threadIdx.x;  // 128 threads
  comb[t]       = ge1[g * 128 + t];
  comb[t + 128] = ge2[g * 128 + t];
  __syncthreads();
  float s = b0[t];
  for (int k = 0; k < 256; ++k) s += comb[k] * W0[k * 128 + t];
  hc[t] = fmaxf(s, 0.f);
  __syncthreads();
  if (t < 10) {
    float s2 = b1[t];
    for (int k = 0; k < 128; ++k) s2 += hc[k] * W1[k * 10 + t];
    out[g * 10 + t] = s2;
  }
}

extern "C" void kernel_launch(void* const* d_in, const int* in_sizes, int n_in,
                              void* d_out, int out_size, void* d_ws, size_t ws_size,
                              hipStream_t stream)
{
  (void)n_in; (void)out_size; (void)ws_size;
  const float* x       = (const float*)d_in[0];
  const float* g1_W1_0 = (const float*)d_in[1];
  const float* g1_W2_0 = (const float*)d_in[2];
  const float* g1_W1_1 = (const float*)d_in[3];
  const float* g1_W2_1 = (const float*)d_in[4];
  const float* g1_W1_2 = (const float*)d_in[5];
  const float* g1_W2_2 = (const float*)d_in[6];
  const float* k_W1_0  = (const float*)d_in[7];   // [257,128]
  const float* k_W2_0  = (const float*)d_in[8];   // [257,128]
  const float* k_W1_1  = (const float*)d_in[9];   // [128,128]
  const float* k_W2_1  = (const float*)d_in[10];  // [128,128]
  const float* c_W0    = (const float*)d_in[11];
  const float* c_b0    = (const float*)d_in[12];
  const float* c_W1    = (const float*)d_in[13];
  const float* c_b1    = (const float*)d_in[14];
  const float* iso     = (const float*)d_in[15];  // [P]
  const int*   ei      = (const int*)d_in[16];    // [2,E1]
  const int*   pu      = (const int*)d_in[18];    // [P]
  const int*   pv      = (const int*)d_in[19];    // [P]
  const int*   te      = (const int*)d_in[20];    // [2,E2]

  const int N  = in_sizes[0] / 64;   // 4096
  const int E1 = in_sizes[16] / 2;
  const int P  = in_sizes[18];       // 129024
  const int E2 = in_sizes[20] / 2;
  const int B  = 64;
  const int ppg = P / B;             // 2016

  const size_t NH = (size_t)N * 128;
  const size_t PH = (size_t)P * 128;

  float* ge1 = (float*)d_ws;          // 8192
  float* ge2 = ge1 + 8192;            // 8192 (contiguous with ge1)
  unsigned short* xb   = (unsigned short*)(ge2 + 8192);  // N*64
  unsigned short* hb   = xb + (size_t)N * 64;  // NH
  unsigned short* preN = hb + NH;              // NH
  unsigned short* msgN = preN + NH;            // NH
  unsigned short* HU1  = msgN + NH;            // NH
  unsigned short* HV1  = HU1 + NH;             // NH
  unsigned short* HU2  = HV1 + NH;             // NH
  unsigned short* HV2  = HU2 + NH;             // NH
  unsigned short* H2   = HV2 + NH;             // PH
  unsigned short* PRE2 = H2 + PH;              // PH
  unsigned short* MSG2 = PRE2 + PH;            // PH
  unsigned short* Wf0  = MSG2 + PH;            // 16384 (K=64)
  unsigned short* Wf1  = Wf0 + 16384;          // 32768 each
  unsigned short* Wf2  = Wf1 + 32768;
  unsigned short* Wf3  = Wf2 + 32768;
  unsigned short* Wf4  = Wf3 + 32768;
  unsigned short* Wf5  = Wf4 + 32768;

  size_t ipOff = ((size_t)((char*)(Wf5 + 32768) - (char*)d_ws) + 15) & ~(size_t)15;
  int4* recP = (int4*)((char*)d_ws + ipOff);   // E2 records (16B aligned)
  int* degN  = (int*)(recP + E2);    // N   } contiguous (zeroed together)
  int* degP  = degN + N;             // P   }
  int* offN  = degP + P;             // N+1
  int* curN  = offN + N + 1;         // N
  int* eidxN = curN + N;             // E1
  int* offP  = eidxN + E1;           // P+1
  int* curP  = offP + P + 1;         // P
  int* bsumN = curP + P;             // 256
  int* bsumP = bsumN + 256;          // 256
  int* cnt   = bsumP + 256;          // 1 (barrier counter)

  // barrier counter must start at 0 (ws is poisoned each call)
  hipMemsetAsync(cnt, 0, 4, stream);

  PArgs a;
  a.x = x;
  a.wa[0] = g1_W1_0;           a.wb[0] = g1_W2_0;
  a.wa[1] = g1_W1_1;           a.wb[1] = g1_W2_1;
  a.wa[2] = g1_W1_2;           a.wb[2] = g1_W2_2;
  a.wa[3] = k_W1_0;            a.wb[3] = k_W2_0;
  a.wa[4] = k_W1_0 + 128*128;  a.wb[4] = k_W2_0 + 128*128;
  a.wa[5] = k_W1_1;            a.wb[5] = k_W2_1;
  a.ei = ei; a.te = te; a.pu = pu; a.pv = pv; a.iso = iso;
  a.xb = xb; a.hb = hb; a.preN = preN; a.msgN = msgN;
  a.HU1 = HU1; a.HV1 = HV1; a.HU2 = HU2; a.HV2 = HV2;
  a.Wf[0] = Wf0; a.Wf[1] = Wf1; a.Wf[2] = Wf2;
  a.Wf[3] = Wf3; a.Wf[4] = Wf4; a.Wf[5] = Wf5;
  a.degN = degN; a.degP = degP; a.offN = offN; a.curN = curN; a.eidxN = eidxN;
  a.offP = offP; a.curP = curP; a.recP = recP;
  a.bsumP = bsumP; a.bsumN = bsumN;
  a.ge1 = ge1; a.ge2 = ge2; a.cnt = cnt;
  a.N = N; a.E1 = E1; a.P = P; a.E2 = E2;

  persist_all<<<256, 256, 0, stream>>>(a);

  gather_two0_bf<<<(P + 7) / 8, 256, 0, stream>>>(HU1, HV1, HU2, HV2, iso,
                                                  k_W1_0 + 256 * 128, k_W2_0 + 256 * 128,
                                                  pu, pv, offP, recP, H2, P);

  gemm_dual_mfma4<<<P / 64, 256, 0, stream>>>(H2, Wf5, PRE2, MSG2);

  gather_rec_segsum<<<B * 16, 256, 0, stream>>>(PRE2, MSG2, offP, recP, ge2, ppg);

  classifier<<<B, 128, 0, stream>>>(ge1, ge2, c_W0, c_b0, c_W1, c_b1, (float*)d_out);
}

// Round 7
// 319.105 us; speedup vs baseline: 2.2363x; 2.2363x over previous
//
#include <hip/hip_runtime.h>
#include <hip/hip_bf16.h>

// Hierarchical 1-2-GNN forward. B=64 graphs x 64 nodes, P=129024 pairs, HID=128.
// Round 7: revert the spin-barrier persistent kernel (R6 pathology: cross-XCD
// polling starved the fabric). Instead exploit graph-locality: node graph edges
// never cross graphs and edge_index is graph-major, so ONE 64-block kernel runs
// the whole node stage in LDS (local CSR, 3 MP layers, seg_sum->ge1 exact,
// HU/HV GEMMs) with only __syncthreads. Pair stage = R5 kernels + R6's fused
// gather+segsum. 11 launches total.

typedef short s16x8 __attribute__((ext_vector_type(8)));
typedef float f32x4 __attribute__((ext_vector_type(4)));

__device__ __forceinline__ unsigned short f2bf(float f) {
  union { float f; unsigned u; } x; x.f = f;
  unsigned r = (x.u + 0x7fffu + ((x.u >> 16) & 1u)) >> 16;   // RNE
  return (unsigned short)r;
}
__device__ __forceinline__ float bf2f(unsigned short h) {
  union { unsigned u; float f; } x; x.u = ((unsigned)h) << 16;
  return x.f;
}
__device__ __forceinline__ float4 ldbf4(const unsigned short* p) {
  ushort4 q = *(const ushort4*)p;
  return make_float4(bf2f(q.x), bf2f(q.y), bf2f(q.z), bf2f(q.w));
}
__device__ __forceinline__ void stbf4(unsigned short* p, float4 v) {
  ushort4 q;
  q.x = f2bf(v.x); q.y = f2bf(v.y); q.z = f2bf(v.z); q.w = f2bf(v.w);
  *(ushort4*)p = q;
}
__device__ __forceinline__ float4 ld4(const float* p) { return *(const float4*)p; }

// ================= dual MFMA core, A from LDS =================
// A is [64][ASTR] ushort; wave wv owns rows wv*16+(lane&15).
template<int KCS, int ASTR>
__device__ __forceinline__ void mfma_dual_lds(
    const unsigned short* A, const unsigned short* Wfrag,
    f32x4 (&accA)[8], f32x4 (&accB)[8])
{
  const int lane = threadIdx.x & 63;
  const int wv = threadIdx.x >> 6;
  const int row = wv * 16 + (lane & 15);
  const int k0 = (lane >> 4) << 3;
  const unsigned short* ap = A + row * ASTR + k0;
  const unsigned short* wp = Wfrag + (size_t)lane * 8;
#pragma unroll
  for (int i = 0; i < 8; ++i) { accA[i] = (f32x4)0.f; accB[i] = (f32x4)0.f; }
#pragma unroll
  for (int kc = 0; kc < KCS; ++kc) {
    s16x8 af = *(const s16x8*)(ap + kc * 32);
#pragma unroll
    for (int nt = 0; nt < 8; ++nt) {
      s16x8 b0 = *(const s16x8*)(wp + ((size_t)((nt)*KCS + kc) << 9));
      s16x8 b1 = *(const s16x8*)(wp + ((size_t)((8 + nt) * KCS + kc) << 9));
      accA[nt] = __builtin_amdgcn_mfma_f32_16x16x32_bf16(af, b0, accA[nt], 0, 0, 0);
      accB[nt] = __builtin_amdgcn_mfma_f32_16x16x32_bf16(af, b1, accB[nt], 0, 0, 0);
    }
  }
}

// epilogue: write both accumulators into LDS row-major (stride 136)
__device__ __forceinline__ void epi_lds(const f32x4 (&accA)[8], const f32x4 (&accB)[8],
    unsigned short (*preS)[136], unsigned short (*msgS)[136])
{
  const int lane = threadIdx.x & 63;
  const int wv = threadIdx.x >> 6;
  const int col = lane & 15;
  const int r0 = wv * 16 + ((lane >> 4) << 2);
  __syncthreads();   // all A-reads (possibly aliasing preS) complete
#pragma unroll
  for (int nt = 0; nt < 8; ++nt)
#pragma unroll
    for (int r = 0; r < 4; ++r) {
      preS[r0 + r][nt * 16 + col] = f2bf(accA[nt][r]);
      msgS[r0 + r][nt * 16 + col] = f2bf(accB[nt][r]);
    }
  __syncthreads();
}

// epilogue: stage through LDS, coalesced bf16 stores to two global outputs
__device__ __forceinline__ void epi_global(const f32x4 (&accA)[8], const f32x4 (&accB)[8],
    unsigned short (*sOut)[136], unsigned short* Ca, unsigned short* Cb, long tile)
{
  const int tid = threadIdx.x;
  const int lane = tid & 63;
  const int wv = tid >> 6;
  const int col = lane & 15;
  const int r0 = wv * 16 + ((lane >> 4) << 2);
  const long rowBase = tile * 64;
#pragma unroll
  for (int sel = 0; sel < 2; ++sel) {
    __syncthreads();
#pragma unroll
    for (int nt = 0; nt < 8; ++nt) {
#pragma unroll
      for (int r = 0; r < 4; ++r)
        sOut[r0 + r][nt * 16 + col] = f2bf(sel ? accB[nt][r] : accA[nt][r]);
    }
    __syncthreads();
    unsigned short* C = sel ? Cb : Ca;
#pragma unroll
    for (int i = 0; i < 4; ++i) {
      int fi = tid + i * 256;
      int row = fi >> 4;
      int c8 = fi & 15;
      *(uint4*)(C + (rowBase + row) * 128 + c8 * 8) = *(uint4*)&sOut[row][c8 * 8];
    }
  }
}

// ================= node stage: one block per graph =================
struct NArgs {
  const float* x;
  const int* ei;            // [2,E1]
  const int* gstart;        // [65] edge-slice bounds per graph
  const unsigned short *Wf0, *Wf1, *Wf2, *Wf3, *Wf4;
  unsigned short *HU1, *HV1, *HU2, *HV2;
  float* ge1;
  int E1;
};

__global__ __launch_bounds__(256) void node_stage(NArgs a)
{
  __shared__ __align__(16) unsigned short hS[64][136];
  __shared__ __align__(16) unsigned short preS[64][136];
  __shared__ __align__(16) unsigned short msgS[64][136];
  __shared__ int ldeg[64], lcur[64], loff[65];
  __shared__ unsigned short ledge[1024];
  __shared__ float sge[128];

  const int b = blockIdx.x;
  const int t = threadIdx.x;
  const int base = b * 64;

  // ---- local CSR build from this graph's edge slice ----
  const int es = a.gstart[b], ee = a.gstart[b + 1];
  if (t < 64) ldeg[t] = 0;
  if (t < 128) sge[t] = 0.f;
  __syncthreads();
  for (int i = es + t; i < ee; i += 256)
    atomicAdd(&ldeg[a.ei[a.E1 + i] - base], 1);          // dst degree
  __syncthreads();
  if (t < 64) {
    int v = ldeg[t], s = v;
#pragma unroll
    for (int d = 1; d < 64; d <<= 1) {
      int o = __shfl_up(s, d, 64);
      if (t >= d) s += o;
    }
    loff[t] = s - v;
    lcur[t] = s - v;
    if (t == 63) loff[64] = s;
  }
  // stage x (fp32 -> bf16) into xs (aliases preS; stride 72 for K=64 MFMA reads)
  unsigned short* xs = &preS[0][0];
  for (int i = t; i < 64 * 64; i += 256) {
    int r = i >> 6, c = i & 63;
    xs[r * 72 + c] = f2bf(a.x[(size_t)(base + r) * 64 + c]);
  }
  __syncthreads();
  for (int i = es + t; i < ee; i += 256) {
    int s = a.ei[i] - base, d = a.ei[a.E1 + i] - base;
    int pos = atomicAdd(&lcur[d], 1);
    ledge[pos] = (unsigned short)s;
  }
  __syncthreads();

  f32x4 accA[8], accB[8];
  const int grp = t >> 5, f = (t & 31) * 4;

  // ---- layer 0 (K=64, A = xs) ----
  mfma_dual_lds<2, 72>(xs, a.Wf0, accA, accB);
  epi_lds(accA, accB, preS, msgS);          // overwrites xs only after sync
  for (int r = grp; r < 64; r += 8) {
    float4 acc = ldbf4(&preS[r][f]);
    int j1 = loff[r + 1];
    for (int j = loff[r]; j < j1; ++j) {
      float4 m = ldbf4(&msgS[ledge[j]][f]);
      acc.x += m.x; acc.y += m.y; acc.z += m.z; acc.w += m.w;
    }
    stbf4(&hS[r][f], make_float4(fmaxf(acc.x, 0.f), fmaxf(acc.y, 0.f),
                                 fmaxf(acc.z, 0.f), fmaxf(acc.w, 0.f)));
  }
  __syncthreads();

  // ---- layer 1 ----
  mfma_dual_lds<4, 136>(&hS[0][0], a.Wf1, accA, accB);
  epi_lds(accA, accB, preS, msgS);
  for (int r = grp; r < 64; r += 8) {
    float4 acc = ldbf4(&preS[r][f]);
    int j1 = loff[r + 1];
    for (int j = loff[r]; j < j1; ++j) {
      float4 m = ldbf4(&msgS[ledge[j]][f]);
      acc.x += m.x; acc.y += m.y; acc.z += m.z; acc.w += m.w;
    }
    stbf4(&hS[r][f], make_float4(fmaxf(acc.x, 0.f), fmaxf(acc.y, 0.f),
                                 fmaxf(acc.z, 0.f), fmaxf(acc.w, 0.f)));
  }
  __syncthreads();

  // ---- layer 2 (+ seg_sum -> ge1, exact, no global atomics) ----
  mfma_dual_lds<4, 136>(&hS[0][0], a.Wf2, accA, accB);
  epi_lds(accA, accB, preS, msgS);
  {
    float4 g = make_float4(0.f, 0.f, 0.f, 0.f);
    for (int r = grp; r < 64; r += 8) {
      float4 acc = ldbf4(&preS[r][f]);
      int j1 = loff[r + 1];
      for (int j = loff[r]; j < j1; ++j) {
        float4 m = ldbf4(&msgS[ledge[j]][f]);
        acc.x += m.x; acc.y += m.y; acc.z += m.z; acc.w += m.w;
      }
      float4 o = make_float4(fmaxf(acc.x, 0.f), fmaxf(acc.y, 0.f),
                             fmaxf(acc.z, 0.f), fmaxf(acc.w, 0.f));
      stbf4(&hS[r][f], o);
      g.x += o.x; g.y += o.y; g.z += o.z; g.w += o.w;
    }
    atomicAdd(&sge[f + 0], g.x);
    atomicAdd(&sge[f + 1], g.y);
    atomicAdd(&sge[f + 2], g.z);
    atomicAdd(&sge[f + 3], g.w);
  }
  __syncthreads();
  if (t < 128) a.ge1[b * 128 + t] = sge[t];

  // ---- HU/HV GEMMs (h @ kW1_0/kW2_0 halves) ----
  mfma_dual_lds<4, 136>(&hS[0][0], a.Wf3, accA, accB);
  epi_global(accA, accB, preS, a.HU1, a.HU2, b);
  mfma_dual_lds<4, 136>(&hS[0][0], a.Wf4, accA, accB);
  epi_global(accA, accB, preS, a.HV1, a.HV2, b);
}

// ================= prep: weight swizzle + ge2 zero + pair-CSR count + edge bounds =================
struct PrepArgs {
  const float* wa[6];
  const float* wb[6];
  unsigned short* Wf[6];
  float* ge2;
  const int* te; int E2;
  int* degP;
  const int* ei; int E1;
  int* gstart;              // [65]
  int nCnt;                 // blocks for count
};

__global__ void prep(PrepArgs p)
{
  int bb = blockIdx.x, t = threadIdx.x;
  if (bb < 88) {
    int gid = bb * 256 + t;
    if (gid < 22528) {
      int pi, local, kcs, kclog;
      if (gid < 2048) { pi = 0; local = gid; kcs = 2; kclog = 1; }
      else { int r = gid - 2048; pi = 1 + (r >> 12); local = r & 4095; kcs = 4; kclog = 2; }
      int lane = local & 63;
      int t1 = local >> 6;
      int kc = t1 & (kcs - 1);
      int t2 = t1 >> kclog;
      int nt = t2 & 7;
      int wsel = t2 >> 3;
      const float* W = wsel ? p.wb[pi] : p.wa[pi];
      int k0 = kc * 32 + ((lane >> 4) << 3);
      int n = nt * 16 + (lane & 15);
      unsigned short tmp[8];
#pragma unroll
      for (int j = 0; j < 8; ++j) tmp[j] = f2bf(W[(size_t)(k0 + j) * 128 + n]);
      *(uint4*)(p.Wf[pi] + (size_t)local * 8) = *(uint4*)tmp;
    }
  } else if (bb < 120) {
    int i = (bb - 88) * 256 + t;
    if (i < 8192) p.ge2[i] = 0.f;
  } else if (bb < 120 + p.nCnt) {
    int e = (bb - 120) * 256 + t;
    if (e < p.E2) atomicAdd(&p.degP[p.te[p.E2 + e]], 1);
  } else {
    int e = (bb - 120 - p.nCnt) * 256 + t;
    if (e <= p.E1) {
      int ge = (e < p.E1) ? (p.ei[e] >> 6) : 64;        // src graph (graph-major)
      int gp = (e > 0) ? (p.ei[e - 1] >> 6) : -1;
      for (int g = gp + 1; g <= ge; ++g) p.gstart[g] = e;
    }
  }
}

// ================= pair-CSR scan + fill =================
__global__ __launch_bounds__(256) void scan_reduce(const int* __restrict__ deg,
                                                   int* __restrict__ bsum, int n)
{
  __shared__ int s[256];
  int b = blockIdx.x, t = threadIdx.x;
  int base = b * 1024;
  int v = 0;
#pragma unroll
  for (int i = 0; i < 4; ++i) {
    int idx = base + t + i * 256;
    if (idx < n) v += deg[idx];
  }
  s[t] = v;
  __syncthreads();
  for (int d = 128; d > 0; d >>= 1) {
    if (t < d) s[t] += s[t + d];
    __syncthreads();
  }
  if (t == 0) bsum[b] = s[0];
}

__global__ __launch_bounds__(1024) void scan_partials(int* __restrict__ bsum, int nb)
{
  __shared__ int s[1024];
  int t = threadIdx.x;
  s[t] = (t < nb) ? bsum[t] : 0;
  __syncthreads();
  for (int d = 1; d < 1024; d <<= 1) {
    int v = (t >= d) ? s[t - d] : 0;
    __syncthreads();
    s[t] += v;
    __syncthreads();
  }
  if (t < nb) bsum[t] = (t == 0) ? 0 : s[t - 1];
  if (t == 1023) bsum[nb] = s[1023];
}

__global__ __launch_bounds__(256) void scan_final(const int* __restrict__ deg,
                                                  const int* __restrict__ bsum,
                                                  int* __restrict__ off,
                                                  int* __restrict__ cur, int n, int nb)
{
  __shared__ int s[256];
  int b = blockIdx.x, t = threadIdx.x;
  int base = b * 1024 + t * 4;
  int v0 = 0, v1 = 0, v2 = 0, v3 = 0;
  if (base + 0 < n) v0 = deg[base + 0];
  if (base + 1 < n) v1 = deg[base + 1];
  if (base + 2 < n) v2 = deg[base + 2];
  if (base + 3 < n) v3 = deg[base + 3];
  s[t] = v0 + v1 + v2 + v3;
  __syncthreads();
  for (int d = 1; d < 256; d <<= 1) {
    int v = (t >= d) ? s[t - d] : 0;
    __syncthreads();
    s[t] += v;
    __syncthreads();
  }
  int run = bsum[b] + ((t == 0) ? 0 : s[t - 1]);
  if (base + 0 < n) { off[base + 0] = run; cur[base + 0] = run; run += v0; }
  if (base + 1 < n) { off[base + 1] = run; cur[base + 1] = run; run += v1; }
  if (base + 2 < n) { off[base + 2] = run; cur[base + 2] = run; run += v2; }
  if (base + 3 < n) { off[base + 3] = run; cur[base + 3] = run; run += v3; }
  if (b == 0 && t == 0) off[n] = bsum[nb];
}

__global__ void csr_fill_pair(const int* __restrict__ te, int E2,
                              const int* __restrict__ pu, const int* __restrict__ pv,
                              const float* __restrict__ iso,
                              int* __restrict__ curP, int4* __restrict__ recP)
{
  int e = blockIdx.x * 256 + threadIdx.x;
  if (e >= E2) return;
  int s = te[e], d = te[E2 + e];
  int pos = atomicAdd(&curP[d], 1);
  recP[pos] = make_int4(pu[s], pv[s], __float_as_int(iso[s]), s);
}

// ================= pair stage =================
__global__ __launch_bounds__(256) void gemm_dual_mfma4(
    const unsigned short* __restrict__ A, const unsigned short* __restrict__ Wfrag,
    unsigned short* __restrict__ Ca, unsigned short* __restrict__ Cb)
{
  __shared__ __align__(16) unsigned short sA[64][136];   // staging for A? no - direct
  const int tid = threadIdx.x;
  const int lane = tid & 63;
  const int wv = tid >> 6;
  const long rowBase = (long)blockIdx.x * 64;

  f32x4 accA[8], accB[8];
#pragma unroll
  for (int i = 0; i < 8; ++i) { accA[i] = (f32x4)0.f; accB[i] = (f32x4)0.f; }

  const unsigned short* aptr =
      A + (size_t)(rowBase + wv * 16 + (lane & 15)) * 128 + ((lane >> 4) << 3);
  const unsigned short* wptr = Wfrag + (size_t)lane * 8;

#pragma unroll
  for (int kc = 0; kc < 4; ++kc) {
    s16x8 af = *(const s16x8*)(aptr + kc * 32);
#pragma unroll
    for (int nt = 0; nt < 8; ++nt) {
      s16x8 b0 = *(const s16x8*)(wptr + ((size_t)((nt)*4 + kc) << 9));
      s16x8 b1 = *(const s16x8*)(wptr + ((size_t)((8 + nt) * 4 + kc) << 9));
      accA[nt] = __builtin_amdgcn_mfma_f32_16x16x32_bf16(af, b0, accA[nt], 0, 0, 0);
      accB[nt] = __builtin_amdgcn_mfma_f32_16x16x32_bf16(af, b1, accB[nt], 0, 0, 0);
    }
  }
  epi_global(accA, accB, sA, Ca, Cb, blockIdx.x);
}

__global__ __launch_bounds__(256) void gather_two0_bf(
    const unsigned short* __restrict__ HU1, const unsigned short* __restrict__ HV1,
    const unsigned short* __restrict__ HU2, const unsigned short* __restrict__ HV2,
    const float* __restrict__ iso,
    const float* __restrict__ w1iso, const float* __restrict__ w2iso,
    const int* __restrict__ pu, const int* __restrict__ pv,
    const int* __restrict__ off, const int4* __restrict__ rec,
    unsigned short* __restrict__ out, int P)
{
  int p = blockIdx.x * 8 + (threadIdx.x >> 5);
  if (p >= P) return;
  int f = (threadIdx.x & 31) * 4;
  float4 wi1 = ld4(w1iso + f);
  float4 wi2 = ld4(w2iso + f);
  int u0 = pu[p], v0 = pv[p];
  float is0 = iso[p];
  float4 a = ldbf4(HU1 + (size_t)u0 * 128 + f);
  float4 b = ldbf4(HV1 + (size_t)v0 * 128 + f);
  float4 acc;
  acc.x = a.x + b.x + is0 * wi1.x;
  acc.y = a.y + b.y + is0 * wi1.y;
  acc.z = a.z + b.z + is0 * wi1.z;
  acc.w = a.w + b.w + is0 * wi1.w;
  int j = off[p], e1 = off[p + 1];
  for (; j + 1 < e1; j += 2) {
    int4 r0 = rec[j], r1 = rec[j + 1];
    float4 mu0 = ldbf4(HU2 + (size_t)r0.x * 128 + f);
    float4 mv0 = ldbf4(HV2 + (size_t)r0.y * 128 + f);
    float4 mu1 = ldbf4(HU2 + (size_t)r1.x * 128 + f);
    float4 mv1 = ldbf4(HV2 + (size_t)r1.y * 128 + f);
    float i0 = __int_as_float(r0.z), i1 = __int_as_float(r1.z);
    acc.x += mu0.x + mv0.x + i0 * wi2.x + mu1.x + mv1.x + i1 * wi2.x;
    acc.y += mu0.y + mv0.y + i0 * wi2.y + mu1.y + mv1.y + i1 * wi2.y;
    acc.z += mu0.z + mv0.z + i0 * wi2.z + mu1.z + mv1.z + i1 * wi2.z;
    acc.w += mu0.w + mv0.w + i0 * wi2.w + mu1.w + mv1.w + i1 * wi2.w;
  }
  if (j < e1) {
    int4 r0 = rec[j];
    float4 mu0 = ldbf4(HU2 + (size_t)r0.x * 128 + f);
    float4 mv0 = ldbf4(HV2 + (size_t)r0.y * 128 + f);
    float i0 = __int_as_float(r0.z);
    acc.x += mu0.x + mv0.x + i0 * wi2.x;
    acc.y += mu0.y + mv0.y + i0 * wi2.y;
    acc.z += mu0.z + mv0.z + i0 * wi2.z;
    acc.w += mu0.w + mv0.w + i0 * wi2.w;
  }
  stbf4(out + (size_t)p * 128 + f,
        make_float4(fmaxf(acc.x, 0.f), fmaxf(acc.y, 0.f),
                    fmaxf(acc.z, 0.f), fmaxf(acc.w, 0.f)));
}

// final pair layer gather+relu fused with segment sum into ge2 (no H2 rewrite)
__global__ __launch_bounds__(256) void gather_rec_segsum(
    const unsigned short* __restrict__ pre, const unsigned short* __restrict__ msg,
    const int* __restrict__ off, const int4* __restrict__ rec,
    float* __restrict__ ge2, int ppg)
{
  __shared__ float sF[128];
  int t = threadIdx.x;
  if (t < 128) sF[t] = 0.f;
  __syncthreads();
  int g = blockIdx.x >> 4;
  int sub = blockIdx.x & 15;
  int r0 = g * ppg + sub * 126;
  int grp = t >> 5;
  int f = (t & 31) * 4;
  float4 gacc = make_float4(0.f, 0.f, 0.f, 0.f);
  for (int rr = grp; rr < 126; rr += 8) {
    int r = r0 + rr;
    float4 acc = ldbf4(pre + (size_t)r * 128 + f);
    int j = off[r], e1 = off[r + 1];
    for (; j + 1 < e1; j += 2) {
      int4 q0 = rec[j], q1 = rec[j + 1];
      float4 m0 = ldbf4(msg + (size_t)q0.w * 128 + f);
      float4 m1 = ldbf4(msg + (size_t)q1.w * 128 + f);
      acc.x += m0.x + m1.x; acc.y += m0.y + m1.y;
      acc.z += m0.z + m1.z; acc.w += m0.w + m1.w;
    }
    if (j < e1) {
      int4 q0 = rec[j];
      float4 m0 = ldbf4(msg + (size_t)q0.w * 128 + f);
      acc.x += m0.x; acc.y += m0.y; acc.z += m0.z; acc.w += m0.w;
    }
    gacc.x += fmaxf(acc.x, 0.f); gacc.y += fmaxf(acc.y, 0.f);
    gacc.z += fmaxf(acc.z, 0.f); gacc.w += fmaxf(acc.w, 0.f);
  }
  atomicAdd(&sF[f + 0], gacc.x);
  atomicAdd(&sF[f + 1], gacc.y);
  atomicAdd(&sF[f + 2], gacc.z);
  atomicAdd(&sF[f + 3], gacc.w);
  __syncthreads();
  if (t < 128) atomicAdd(&ge2[g * 128 + t], sF[t]);
}

__global__ void classifier(const float* __restrict__ ge1, const float* __restrict__ ge2,
                           const float* __restrict__ W0, const float* __restrict__ b0,
                           const float* __restrict__ W1, const float* __restrict__ b1,
                           float* __restrict__ out)
{
  __shared__ float comb[256];
  __shared__ float hc[128];
  int g = blockIdx.x, t = threadIdx.x;  // 128 threads
  comb[t]       = ge1[g * 128 + t];
  comb[t + 128] = ge2[g * 128 + t];
  __syncthreads();
  float s = b0[t];
  for (int k = 0; k < 256; ++k) s += comb[k] * W0[k * 128 + t];
  hc[t] = fmaxf(s, 0.f);
  __syncthreads();
  if (t < 10) {
    float s2 = b1[t];
    for (int k = 0; k < 128; ++k) s2 += hc[k] * W1[k * 10 + t];
    out[g * 10 + t] = s2;
  }
}

extern "C" void kernel_launch(void* const* d_in, const int* in_sizes, int n_in,
                              void* d_out, int out_size, void* d_ws, size_t ws_size,
                              hipStream_t stream)
{
  (void)n_in; (void)out_size; (void)ws_size;
  const float* x       = (const float*)d_in[0];
  const float* g1_W1_0 = (const float*)d_in[1];
  const float* g1_W2_0 = (const float*)d_in[2];
  const float* g1_W1_1 = (const float*)d_in[3];
  const float* g1_W2_1 = (const float*)d_in[4];
  const float* g1_W1_2 = (const float*)d_in[5];
  const float* g1_W2_2 = (const float*)d_in[6];
  const float* k_W1_0  = (const float*)d_in[7];   // [257,128]
  const float* k_W2_0  = (const float*)d_in[8];   // [257,128]
  const float* k_W1_1  = (const float*)d_in[9];   // [128,128]
  const float* k_W2_1  = (const float*)d_in[10];  // [128,128]
  const float* c_W0    = (const float*)d_in[11];
  const float* c_b0    = (const float*)d_in[12];
  const float* c_W1    = (const float*)d_in[13];
  const float* c_b1    = (const float*)d_in[14];
  const float* iso     = (const float*)d_in[15];  // [P]
  const int*   ei      = (const int*)d_in[16];    // [2,E1]
  const int*   pu      = (const int*)d_in[18];    // [P]
  const int*   pv      = (const int*)d_in[19];    // [P]
  const int*   te      = (const int*)d_in[20];    // [2,E2]

  const int N  = in_sizes[0] / 64;   // 4096
  const int E1 = in_sizes[16] / 2;
  const int P  = in_sizes[18];       // 129024
  const int E2 = in_sizes[20] / 2;
  const int B  = 64;
  const int ppg = P / B;             // 2016

  const size_t NH = (size_t)N * 128;
  const size_t PH = (size_t)P * 128;

  float* ge1 = (float*)d_ws;                    // 8192
  float* ge2 = ge1 + 8192;                      // 8192
  unsigned short* HU1 = (unsigned short*)(ge2 + 8192);  // NH each
  unsigned short* HV1 = HU1 + NH;
  unsigned short* HU2 = HV1 + NH;
  unsigned short* HV2 = HU2 + NH;
  unsigned short* H2   = HV2 + NH;              // PH
  unsigned short* PRE2 = H2 + PH;               // PH
  unsigned short* MSG2 = PRE2 + PH;             // PH
  unsigned short* Wf0  = MSG2 + PH;             // 16384
  unsigned short* Wf1  = Wf0 + 16384;           // 32768 each
  unsigned short* Wf2  = Wf1 + 32768;
  unsigned short* Wf3  = Wf2 + 32768;
  unsigned short* Wf4  = Wf3 + 32768;
  unsigned short* Wf5  = Wf4 + 32768;

  size_t ipOff = ((size_t)((char*)(Wf5 + 32768) - (char*)d_ws) + 15) & ~(size_t)15;
  int4* recP   = (int4*)((char*)d_ws + ipOff);  // E2 records
  int* degP    = (int*)(recP + E2);             // P
  int* offP    = degP + P;                      // P+1
  int* curP    = offP + P + 1;                  // P
  int* bsumP   = curP + P;                      // 128
  int* gstartN = bsumP + 128;                   // 65

  const int nbP  = (P + 1023) / 1024;           // 126
  const int nCnt = (E2 + 255) / 256;
  const int nBnd = (E1 + 256) / 256;            // covers e in [0,E1]

  // 1) zero pair degrees
  hipMemsetAsync(degP, 0, (size_t)P * 4, stream);

  // 2) prep: swizzle 6 weight pairs + zero ge2 + count pair in-degrees + graph bounds
  PrepArgs pa;
  pa.wa[0] = g1_W1_0;           pa.wb[0] = g1_W2_0;
  pa.wa[1] = g1_W1_1;           pa.wb[1] = g1_W2_1;
  pa.wa[2] = g1_W1_2;           pa.wb[2] = g1_W2_2;
  pa.wa[3] = k_W1_0;            pa.wb[3] = k_W2_0;
  pa.wa[4] = k_W1_0 + 128*128;  pa.wb[4] = k_W2_0 + 128*128;
  pa.wa[5] = k_W1_1;            pa.wb[5] = k_W2_1;
  pa.Wf[0] = Wf0; pa.Wf[1] = Wf1; pa.Wf[2] = Wf2;
  pa.Wf[3] = Wf3; pa.Wf[4] = Wf4; pa.Wf[5] = Wf5;
  pa.ge2 = ge2; pa.te = te; pa.E2 = E2; pa.degP = degP;
  pa.ei = ei; pa.E1 = E1; pa.gstart = gstartN; pa.nCnt = nCnt;
  prep<<<120 + nCnt + nBnd, 256, 0, stream>>>(pa);

  // 3-6) pair CSR: scan + fill (packed records)
  scan_reduce<<<nbP, 256, 0, stream>>>(degP, bsumP, P);
  scan_partials<<<1, 1024, 0, stream>>>(bsumP, nbP);
  scan_final<<<nbP, 256, 0, stream>>>(degP, bsumP, offP, curP, P, nbP);
  csr_fill_pair<<<nCnt, 256, 0, stream>>>(te, E2, pu, pv, iso, curP, recP);

  // 7) whole node stage, one block per graph
  NArgs na;
  na.x = x; na.ei = ei; na.gstart = gstartN; na.E1 = E1;
  na.Wf0 = Wf0; na.Wf1 = Wf1; na.Wf2 = Wf2; na.Wf3 = Wf3; na.Wf4 = Wf4;
  na.HU1 = HU1; na.HU2 = HU2; na.HV1 = HV1; na.HV2 = HV2;
  na.ge1 = ge1;
  node_stage<<<B, 256, 0, stream>>>(na);

  // 8) 2-set layer 0 (fused compose + gather)
  gather_two0_bf<<<(P + 7) / 8, 256, 0, stream>>>(HU1, HV1, HU2, HV2, iso,
                                                  k_W1_0 + 256 * 128, k_W2_0 + 256 * 128,
                                                  pu, pv, offP, recP, H2, P);

  // 9) 2-set layer 1 dual GEMM
  gemm_dual_mfma4<<<P / 64, 256, 0, stream>>>(H2, Wf5, PRE2, MSG2);

  // 10) final gather + relu + segment sum into ge2
  gather_rec_segsum<<<B * 16, 256, 0, stream>>>(PRE2, MSG2, offP, recP, ge2, ppg);

  // 11) classifier
  classifier<<<B, 128, 0, stream>>>(ge1, ge2, c_W0, c_b0, c_W1, c_b1, (float*)d_out);
}